// Round 2
// baseline (1229.632 us; speedup 1.0000x reference)
//
#include <hip/hip_runtime.h>

#define NN 100000
#define NE 1600000
#define HID 128
#define OUT_DIM 10
#define N_CONV 4
#define N_GRAPHS 128
#define NB_SCAN ((NN + 255) / 256)   // 391 scan blocks

// ---------------- prep: zero counters / pool accumulator ----------------

__global__ __launch_bounds__(256) void zero_kernel(int* __restrict__ cnt,
                                                   float* __restrict__ g) {
  int i = blockIdx.x * 256 + threadIdx.x;
  if (i < NN) cnt[i] = 0;
  if (i < N_GRAPHS * HID) g[i] = 0.0f;
}

__global__ __launch_bounds__(256) void cnt_count(const int* __restrict__ col,
                                                 int* __restrict__ cnt) {
  int e = blockIdx.x * 256 + threadIdx.x;
  if (e < NE) atomicAdd(&cnt[col[e]], 1);
}

// ---------------- exclusive scan of cnt -> row_ptr (3 kernels) ----------------

__global__ __launch_bounds__(256) void scan_partial(const int* __restrict__ cnt,
                                                    int* __restrict__ bsum) {
  __shared__ int s[256];
  int i = blockIdx.x * 256 + threadIdx.x;
  int v = (i < NN) ? cnt[i] : 0;
  s[threadIdx.x] = v;
  __syncthreads();
  for (int off = 128; off > 0; off >>= 1) {
    if (threadIdx.x < off) s[threadIdx.x] += s[threadIdx.x + off];
    __syncthreads();
  }
  if (threadIdx.x == 0) bsum[blockIdx.x] = s[0];
}

__global__ __launch_bounds__(512) void scan_bsum(int* __restrict__ bsum) {
  __shared__ int s[512];
  int i = threadIdx.x;
  int v = (i < NB_SCAN) ? bsum[i] : 0;
  s[i] = v;
  __syncthreads();
  for (int off = 1; off < 512; off <<= 1) {
    int t = (i >= off) ? s[i - off] : 0;
    __syncthreads();
    s[i] += t;
    __syncthreads();
  }
  if (i < NB_SCAN) bsum[i] = s[i] - v;  // exclusive
}

__global__ __launch_bounds__(256) void scan_write(const int* __restrict__ cnt,
                                                  const int* __restrict__ bsum,
                                                  int* __restrict__ row_ptr,
                                                  int* __restrict__ cursor,
                                                  float* __restrict__ dinv) {
  __shared__ int s[256];
  int i = blockIdx.x * 256 + threadIdx.x;
  int v = (i < NN) ? cnt[i] : 0;
  s[threadIdx.x] = v;
  __syncthreads();
  for (int off = 1; off < 256; off <<= 1) {
    int t = (threadIdx.x >= off) ? s[threadIdx.x - off] : 0;
    __syncthreads();
    s[threadIdx.x] += t;
    __syncthreads();
  }
  if (i < NN) {
    int excl = bsum[blockIdx.x] + s[threadIdx.x] - v;
    row_ptr[i] = excl;
    cursor[i] = excl;
    dinv[i] = rsqrtf((float)(v + 1));   // +1 self-loop
    if (i == NN - 1) row_ptr[NN] = excl + v;
  }
}

// ---------------- CSR fill (bucket edges by dst, fuse norm) ----------------

__global__ __launch_bounds__(256) void fill_csr(const int* __restrict__ row,
                                                const int* __restrict__ col,
                                                const float* __restrict__ dinv,
                                                int* __restrict__ cursor,
                                                int* __restrict__ csr_src,
                                                float* __restrict__ csr_norm) {
  int e = blockIdx.x * 256 + threadIdx.x;
  if (e >= NE) return;
  int r = row[e], c = col[e];
  int pos = atomicAdd(&cursor[c], 1);
  csr_src[pos] = r;
  csr_norm[pos] = dinv[r] * dinv[c];
}

// ---------------- fp32 GEMM: out[N,128] = A[N,128] @ W[128,128] ----------------

__global__ __launch_bounds__(512) void gemm128(const float* __restrict__ A,
                                               const float* __restrict__ W,
                                               float* __restrict__ out,
                                               const float* __restrict__ bias,
                                               int relu, int N) {
  __shared__ float sA[128][64];
  __shared__ float sW[64][128];
  const int tid = threadIdx.x;
  const int tr = tid >> 5;   // 0..15
  const int tc = tid & 31;   // 0..31
  const int rowBase = blockIdx.x * 128;

  float acc[8][4];
#pragma unroll
  for (int r = 0; r < 8; ++r)
#pragma unroll
    for (int j = 0; j < 4; ++j) acc[r][j] = 0.f;

  for (int kc = 0; kc < 128; kc += 64) {
    {  // stage A tile: 128 rows x 64 k
      int r = tid >> 4;    // 0..31
      int c4 = tid & 15;   // 0..15
#pragma unroll
      for (int i = 0; i < 4; ++i) {
        int row = rowBase + i * 32 + r;
        float4 v = make_float4(0.f, 0.f, 0.f, 0.f);
        if (row < N) v = *(const float4*)&A[(size_t)row * 128 + kc + c4 * 4];
        *(float4*)&sA[i * 32 + r][c4 * 4] = v;
      }
    }
    {  // stage W tile: 64 k x 128 cols
      int k = tid >> 5;    // 0..15
      int c4 = tid & 31;   // 0..31
#pragma unroll
      for (int i = 0; i < 4; ++i) {
        *(float4*)&sW[i * 16 + k][c4 * 4] =
            *(const float4*)&W[(size_t)(kc + i * 16 + k) * 128 + c4 * 4];
      }
    }
    __syncthreads();
#pragma unroll 16
    for (int k = 0; k < 64; ++k) {
      float4 b = *(float4*)&sW[k][tc * 4];
#pragma unroll
      for (int r = 0; r < 8; ++r) {
        float a = sA[tr * 8 + r][k];
        acc[r][0] += a * b.x;
        acc[r][1] += a * b.y;
        acc[r][2] += a * b.z;
        acc[r][3] += a * b.w;
      }
    }
    __syncthreads();
  }

  float4 bv = make_float4(0.f, 0.f, 0.f, 0.f);
  if (bias) bv = *(const float4*)&bias[tc * 4];
#pragma unroll
  for (int r = 0; r < 8; ++r) {
    int row = rowBase + tr * 8 + r;
    if (row < N) {
      float4 v;
      v.x = acc[r][0] + bv.x;
      v.y = acc[r][1] + bv.y;
      v.z = acc[r][2] + bv.z;
      v.w = acc[r][3] + bv.w;
      if (relu) {
        v.x = fmaxf(v.x, 0.f); v.y = fmaxf(v.y, 0.f);
        v.z = fmaxf(v.z, 0.f); v.w = fmaxf(v.w, 0.f);
      }
      *(float4*)&out[(size_t)row * 128 + tc * 4] = v;
    }
  }
}

// ---- fused aggregation: h[i] = relu(sum_in m[src]*norm + m[i]*dinv^2 + bias) ----
// 32 lanes per node, each lane owns one float4 of the 128-wide feature row.

__global__ __launch_bounds__(256) void gather_fused(const float* __restrict__ m,
                                                    const int* __restrict__ row_ptr,
                                                    const int* __restrict__ csr_src,
                                                    const float* __restrict__ csr_norm,
                                                    const float* __restrict__ dinv,
                                                    const float* __restrict__ bias,
                                                    float* __restrict__ h) {
  int t = blockIdx.x * 256 + threadIdx.x;
  int node = t >> 5;
  if (node >= NN) return;
  int lane = t & 31;

  float dn = dinv[node];
  float s2 = dn * dn;
  float4 acc = *(const float4*)&m[(size_t)node * 128 + lane * 4];
  acc.x *= s2; acc.y *= s2; acc.z *= s2; acc.w *= s2;

  int beg = row_ptr[node];
  int end = row_ptr[node + 1];

  // software-pipeline the (src, norm) index loads one iteration ahead
  int s_next = 0; float nv_next = 0.f;
  if (beg < end) { s_next = csr_src[beg]; nv_next = csr_norm[beg]; }
  for (int k = beg; k < end; ++k) {
    int s = s_next; float nv = nv_next;
    if (k + 1 < end) { s_next = csr_src[k + 1]; nv_next = csr_norm[k + 1]; }
    float4 v = *(const float4*)&m[(size_t)s * 128 + lane * 4];
    acc.x += v.x * nv; acc.y += v.y * nv;
    acc.z += v.z * nv; acc.w += v.w * nv;
  }

  float4 b = *(const float4*)&bias[lane * 4];
  float4 o;
  o.x = fmaxf(acc.x + b.x, 0.f);
  o.y = fmaxf(acc.y + b.y, 0.f);
  o.z = fmaxf(acc.z + b.z, 0.f);
  o.w = fmaxf(acc.w + b.w, 0.f);
  *(float4*)&h[(size_t)node * 128 + lane * 4] = o;
}

// ---------------- pooling: g[batch[i]] += h[i], batch sorted ----------------

__global__ __launch_bounds__(128) void pool_kernel(const float* __restrict__ h,
                                                   const int* __restrict__ batch,
                                                   float* __restrict__ g) {
  int d = threadIdx.x;  // column 0..127
  int chunk = (NN + gridDim.x - 1) / gridDim.x;
  int r0 = blockIdx.x * chunk;
  int r1 = min(NN, r0 + chunk);
  if (r0 >= r1) return;
  float acc = 0.f;
  int cur = batch[r0];
  for (int r = r0; r < r1; ++r) {
    int b = batch[r];
    if (b != cur) {
      atomicAdd(&g[(size_t)cur * HID + d], acc);
      acc = 0.f;
      cur = b;
    }
    acc += h[(size_t)r * HID + d];
  }
  atomicAdd(&g[(size_t)cur * HID + d], acc);
}

// ---------------- decode: out[128,10] = g @ dec_W + dec_b ----------------

__global__ __launch_bounds__(256) void decode_kernel(const float* __restrict__ g,
                                                     const float* __restrict__ W,
                                                     const float* __restrict__ b,
                                                     float* __restrict__ out) {
  int idx = blockIdx.x * 256 + threadIdx.x;
  if (idx >= N_GRAPHS * OUT_DIM) return;
  int gi = idx / OUT_DIM;
  int o = idx % OUT_DIM;
  float acc = b[o];
#pragma unroll 8
  for (int k = 0; k < HID; ++k) acc += g[(size_t)gi * HID + k] * W[k * OUT_DIM + o];
  out[idx] = acc;
}

// ---------------- launch ----------------

extern "C" void kernel_launch(void* const* d_in, const int* in_sizes, int n_in,
                              void* d_out, int out_size, void* d_ws, size_t ws_size,
                              hipStream_t stream) {
  const float* x      = (const float*)d_in[0];
  const float* enc_W  = (const float*)d_in[1];
  const float* enc_b  = (const float*)d_in[2];
  const float* conv_W = (const float*)d_in[3];
  const float* conv_b = (const float*)d_in[4];
  const float* dec_W  = (const float*)d_in[5];
  const float* dec_b  = (const float*)d_in[6];
  const int*   erow   = (const int*)d_in[7];            // edge_index[0], sources
  const int*   ecol   = ((const int*)d_in[7]) + NE;     // edge_index[1], targets
  const int*   batch  = (const int*)d_in[8];
  float* out = (float*)d_out;

  // workspace layout (all 4-byte elems)
  float* h       = (float*)d_ws;                    // NN*128
  float* m       = h + (size_t)NN * 128;            // NN*128
  float* dinv    = m + (size_t)NN * 128;            // NN
  float* csr_norm= dinv + ((NN + 255) & ~255);      // NE
  float* g       = csr_norm + NE;                   // N_GRAPHS*HID
  int*   cnt     = (int*)(g + N_GRAPHS * HID);      // NN
  int*   row_ptr = cnt + ((NN + 255) & ~255);       // NN+1
  int*   cursor  = row_ptr + ((NN + 256) & ~255);   // NN
  int*   bsum    = cursor + ((NN + 255) & ~255);    // 512
  int*   csr_src = bsum + 512;                      // NE

  const int gemmBlocks = (NN + 127) / 128;
  const int nodeBlocks = (NN * 32 + 255) / 256;

  // ---- CSR build + norms ----
  zero_kernel<<<(NN + 255) / 256, 256, 0, stream>>>(cnt, g);
  cnt_count<<<(NE + 255) / 256, 256, 0, stream>>>(ecol, cnt);
  scan_partial<<<NB_SCAN, 256, 0, stream>>>(cnt, bsum);
  scan_bsum<<<1, 512, 0, stream>>>(bsum);
  scan_write<<<NB_SCAN, 256, 0, stream>>>(cnt, bsum, row_ptr, cursor, dinv);
  fill_csr<<<(NE + 255) / 256, 256, 0, stream>>>(erow, ecol, dinv, cursor, csr_src, csr_norm);

  // ---- encode ----
  gemm128<<<gemmBlocks, 512, 0, stream>>>(x, enc_W, h, enc_b, 1, NN);

  // ---- conv layers: m = h@W, then fused gather+self+bias+relu ----
  for (int l = 0; l < N_CONV; ++l) {
    const float* Wl = conv_W + (size_t)l * 128 * 128;
    const float* bl = conv_b + (size_t)l * 128;
    gemm128<<<gemmBlocks, 512, 0, stream>>>(h, Wl, m, nullptr, 0, NN);
    gather_fused<<<nodeBlocks, 256, 0, stream>>>(m, row_ptr, csr_src, csr_norm, dinv, bl, h);
  }

  // ---- pooling + decode ----
  pool_kernel<<<256, 128, 0, stream>>>(h, batch, g);
  decode_kernel<<<(N_GRAPHS * OUT_DIM + 255) / 256, 256, 0, stream>>>(g, dec_W, dec_b, out);
}

// Round 3
// 1064.465 us; speedup vs baseline: 1.1552x; 1.1552x over previous
//
#include <hip/hip_runtime.h>

#define NN 100000
#define NE 1600000
#define HID 128
#define OUT_DIM 10
#define N_CONV 4
#define N_GRAPHS 128
#define NB_SCAN ((NN + 255) / 256)   // 391 scan blocks

// ---------------- prep: zero counters / pool accumulator ----------------

__global__ __launch_bounds__(256) void zero_kernel(int* __restrict__ cnt,
                                                   float* __restrict__ g) {
  int i = blockIdx.x * 256 + threadIdx.x;
  if (i < NN) cnt[i] = 0;
  if (i < N_GRAPHS * HID) g[i] = 0.0f;
}

__global__ __launch_bounds__(256) void cnt_count(const int* __restrict__ col,
                                                 int* __restrict__ cnt) {
  int e = blockIdx.x * 256 + threadIdx.x;
  if (e < NE) atomicAdd(&cnt[col[e]], 1);
}

// ---------------- exclusive scan of cnt -> row_ptr (3 kernels) ----------------

__global__ __launch_bounds__(256) void scan_partial(const int* __restrict__ cnt,
                                                    int* __restrict__ bsum) {
  __shared__ int s[256];
  int i = blockIdx.x * 256 + threadIdx.x;
  int v = (i < NN) ? cnt[i] : 0;
  s[threadIdx.x] = v;
  __syncthreads();
  for (int off = 128; off > 0; off >>= 1) {
    if (threadIdx.x < off) s[threadIdx.x] += s[threadIdx.x + off];
    __syncthreads();
  }
  if (threadIdx.x == 0) bsum[blockIdx.x] = s[0];
}

__global__ __launch_bounds__(512) void scan_bsum(int* __restrict__ bsum) {
  __shared__ int s[512];
  int i = threadIdx.x;
  int v = (i < NB_SCAN) ? bsum[i] : 0;
  s[i] = v;
  __syncthreads();
  for (int off = 1; off < 512; off <<= 1) {
    int t = (i >= off) ? s[i - off] : 0;
    __syncthreads();
    s[i] += t;
    __syncthreads();
  }
  if (i < NB_SCAN) bsum[i] = s[i] - v;  // exclusive
}

__global__ __launch_bounds__(256) void scan_write(const int* __restrict__ cnt,
                                                  const int* __restrict__ bsum,
                                                  int* __restrict__ row_ptr,
                                                  int* __restrict__ cursor,
                                                  float* __restrict__ dinv) {
  __shared__ int s[256];
  int i = blockIdx.x * 256 + threadIdx.x;
  int v = (i < NN) ? cnt[i] : 0;
  s[threadIdx.x] = v;
  __syncthreads();
  for (int off = 1; off < 256; off <<= 1) {
    int t = (threadIdx.x >= off) ? s[threadIdx.x - off] : 0;
    __syncthreads();
    s[threadIdx.x] += t;
    __syncthreads();
  }
  if (i < NN) {
    int excl = bsum[blockIdx.x] + s[threadIdx.x] - v;
    row_ptr[i] = excl;
    cursor[i] = excl;
    dinv[i] = rsqrtf((float)(v + 1));   // +1 self-loop
    if (i == NN - 1) row_ptr[NN] = excl + v;
  }
}

// ---------------- CSR fill: bucket edges by dst (src only; norm folded out) ----

__global__ __launch_bounds__(256) void fill_csr(const int* __restrict__ row,
                                                const int* __restrict__ col,
                                                int* __restrict__ cursor,
                                                int* __restrict__ csr_src) {
  int e = blockIdx.x * 256 + threadIdx.x;
  if (e >= NE) return;
  int r = row[e], c = col[e];
  int pos = atomicAdd(&cursor[c], 1);
  csr_src[pos] = r;
}

// ---------------- fp32 GEMM: out[N,128] = A[N,128] @ W[128,128] ----------------
// 256 threads, 128x128 tile, K-tile 32, 8x8 micro-tile per thread.
// All LDS reads are ds_read_b128 with <=2-way bank aliasing:
//  - sA stride 36 floats; thread rows tr+16*i (i=0..7) -> banks differ by 4*tr.
//  - sW stride 132 floats; thread cols {tc*4..+3} and {64+tc*4..+3}.
// Optional epilogue: out = relu(out+bias), and/or scale rows by dinv[row]
// (pre-scaled message m' = (h@W) * dinv for the conv layers).

__global__ __launch_bounds__(256) void gemm128v2(const float* __restrict__ A,
                                                 const float* __restrict__ W,
                                                 float* __restrict__ out,
                                                 const float* __restrict__ bias,
                                                 int relu,
                                                 const float* __restrict__ rowscale,
                                                 int N) {
  __shared__ float sA[128][36];
  __shared__ float sW[32][132];
  const int tid = threadIdx.x;
  const int tr = tid >> 4;   // 0..15
  const int tc = tid & 15;   // 0..15
  const int rowBase = blockIdx.x * 128;

  float4 acc0[8], acc1[8];
#pragma unroll
  for (int r = 0; r < 8; ++r) {
    acc0[r] = make_float4(0.f, 0.f, 0.f, 0.f);
    acc1[r] = make_float4(0.f, 0.f, 0.f, 0.f);
  }

  for (int kc = 0; kc < 128; kc += 32) {
    {  // stage A tile: 128 rows x 32 k, 4 float4 per thread
      int r = tid >> 1;          // 0..127
      int half = tid & 1;        // 0..1
      int row = rowBase + r;
      const float* src = &A[(size_t)row * 128 + kc + half * 16];
#pragma unroll
      for (int j = 0; j < 4; ++j) {
        float4 v = make_float4(0.f, 0.f, 0.f, 0.f);
        if (row < N) v = *(const float4*)&src[j * 4];
        *(float4*)&sA[r][half * 16 + j * 4] = v;
      }
    }
    {  // stage W tile: 32 k x 128 cols, 4 float4 per thread
      int k = tid >> 3;                 // 0..31
      int cg = (tid & 7) * 16;          // 0,16,...,112
      const float* src = &W[(size_t)(kc + k) * 128 + cg];
#pragma unroll
      for (int j = 0; j < 4; ++j) {
        *(float4*)&sW[k][cg + j * 4] = *(const float4*)&src[j * 4];
      }
    }
    __syncthreads();

#pragma unroll
    for (int kk = 0; kk < 32; kk += 4) {
      float4 b0[4], b1[4];
#pragma unroll
      for (int j = 0; j < 4; ++j) {
        b0[j] = *(float4*)&sW[kk + j][tc * 4];
        b1[j] = *(float4*)&sW[kk + j][tc * 4 + 64];
      }
#pragma unroll
      for (int r = 0; r < 8; ++r) {
        float4 a = *(float4*)&sA[tr + 16 * r][kk];
        acc0[r].x += a.x * b0[0].x; acc0[r].y += a.x * b0[0].y;
        acc0[r].z += a.x * b0[0].z; acc0[r].w += a.x * b0[0].w;
        acc1[r].x += a.x * b1[0].x; acc1[r].y += a.x * b1[0].y;
        acc1[r].z += a.x * b1[0].z; acc1[r].w += a.x * b1[0].w;

        acc0[r].x += a.y * b0[1].x; acc0[r].y += a.y * b0[1].y;
        acc0[r].z += a.y * b0[1].z; acc0[r].w += a.y * b0[1].w;
        acc1[r].x += a.y * b1[1].x; acc1[r].y += a.y * b1[1].y;
        acc1[r].z += a.y * b1[1].z; acc1[r].w += a.y * b1[1].w;

        acc0[r].x += a.z * b0[2].x; acc0[r].y += a.z * b0[2].y;
        acc0[r].z += a.z * b0[2].z; acc0[r].w += a.z * b0[2].w;
        acc1[r].x += a.z * b1[2].x; acc1[r].y += a.z * b1[2].y;
        acc1[r].z += a.z * b1[2].z; acc1[r].w += a.z * b1[2].w;

        acc0[r].x += a.w * b0[3].x; acc0[r].y += a.w * b0[3].y;
        acc0[r].z += a.w * b0[3].z; acc0[r].w += a.w * b0[3].w;
        acc1[r].x += a.w * b1[3].x; acc1[r].y += a.w * b1[3].y;
        acc1[r].z += a.w * b1[3].z; acc1[r].w += a.w * b1[3].w;
      }
    }
    __syncthreads();
  }

  float4 bv0 = make_float4(0.f, 0.f, 0.f, 0.f);
  float4 bv1 = make_float4(0.f, 0.f, 0.f, 0.f);
  if (bias) {
    bv0 = *(const float4*)&bias[tc * 4];
    bv1 = *(const float4*)&bias[tc * 4 + 64];
  }
#pragma unroll
  for (int r = 0; r < 8; ++r) {
    int row = rowBase + tr + 16 * r;
    if (row < N) {
      float sc = rowscale ? rowscale[row] : 1.0f;
      float4 v0, v1;
      v0.x = (acc0[r].x + bv0.x) * sc; v0.y = (acc0[r].y + bv0.y) * sc;
      v0.z = (acc0[r].z + bv0.z) * sc; v0.w = (acc0[r].w + bv0.w) * sc;
      v1.x = (acc1[r].x + bv1.x) * sc; v1.y = (acc1[r].y + bv1.y) * sc;
      v1.z = (acc1[r].z + bv1.z) * sc; v1.w = (acc1[r].w + bv1.w) * sc;
      if (relu) {
        v0.x = fmaxf(v0.x, 0.f); v0.y = fmaxf(v0.y, 0.f);
        v0.z = fmaxf(v0.z, 0.f); v0.w = fmaxf(v0.w, 0.f);
        v1.x = fmaxf(v1.x, 0.f); v1.y = fmaxf(v1.y, 0.f);
        v1.z = fmaxf(v1.z, 0.f); v1.w = fmaxf(v1.w, 0.f);
      }
      *(float4*)&out[(size_t)row * 128 + tc * 4] = v0;
      *(float4*)&out[(size_t)row * 128 + tc * 4 + 64] = v1;
    }
  }
}

// ---- fused aggregation: h[i] = relu(dinv_i*(sum_in m'[src] + m'[i]) + bias) ----
// m' is pre-scaled by dinv[src] in the GEMM epilogue.
// 32 lanes per node, each lane owns one float4 of the 128-wide feature row.

__global__ __launch_bounds__(256) void gather_fused(const float* __restrict__ m,
                                                    const int* __restrict__ row_ptr,
                                                    const int* __restrict__ csr_src,
                                                    const float* __restrict__ dinv,
                                                    const float* __restrict__ bias,
                                                    float* __restrict__ h) {
  int t = blockIdx.x * 256 + threadIdx.x;
  int node = t >> 5;
  if (node >= NN) return;
  int lane = t & 31;

  float4 acc = *(const float4*)&m[(size_t)node * 128 + lane * 4];  // self (pre-scaled)

  int beg = row_ptr[node];
  int end = row_ptr[node + 1];

  int s_next = 0;
  if (beg < end) s_next = csr_src[beg];
  for (int k = beg; k < end; ++k) {
    int s = s_next;
    if (k + 1 < end) s_next = csr_src[k + 1];
    float4 v = *(const float4*)&m[(size_t)s * 128 + lane * 4];
    acc.x += v.x; acc.y += v.y; acc.z += v.z; acc.w += v.w;
  }

  float dn = dinv[node];
  float4 b = *(const float4*)&bias[lane * 4];
  float4 o;
  o.x = fmaxf(acc.x * dn + b.x, 0.f);
  o.y = fmaxf(acc.y * dn + b.y, 0.f);
  o.z = fmaxf(acc.z * dn + b.z, 0.f);
  o.w = fmaxf(acc.w * dn + b.w, 0.f);
  *(float4*)&h[(size_t)node * 128 + lane * 4] = o;
}

// ---------------- pooling: g[batch[i]] += h[i], batch sorted ----------------

__global__ __launch_bounds__(128) void pool_kernel(const float* __restrict__ h,
                                                   const int* __restrict__ batch,
                                                   float* __restrict__ g) {
  int d = threadIdx.x;  // column 0..127
  int chunk = (NN + gridDim.x - 1) / gridDim.x;
  int r0 = blockIdx.x * chunk;
  int r1 = min(NN, r0 + chunk);
  if (r0 >= r1) return;
  float acc = 0.f;
  int cur = batch[r0];
  for (int r = r0; r < r1; ++r) {
    int b = batch[r];
    if (b != cur) {
      atomicAdd(&g[(size_t)cur * HID + d], acc);
      acc = 0.f;
      cur = b;
    }
    acc += h[(size_t)r * HID + d];
  }
  atomicAdd(&g[(size_t)cur * HID + d], acc);
}

// ---------------- decode: out[128,10] = g @ dec_W + dec_b ----------------

__global__ __launch_bounds__(256) void decode_kernel(const float* __restrict__ g,
                                                     const float* __restrict__ W,
                                                     const float* __restrict__ b,
                                                     float* __restrict__ out) {
  int idx = blockIdx.x * 256 + threadIdx.x;
  if (idx >= N_GRAPHS * OUT_DIM) return;
  int gi = idx / OUT_DIM;
  int o = idx % OUT_DIM;
  float acc = b[o];
#pragma unroll 8
  for (int k = 0; k < HID; ++k) acc += g[(size_t)gi * HID + k] * W[k * OUT_DIM + o];
  out[idx] = acc;
}

// ---------------- launch ----------------

extern "C" void kernel_launch(void* const* d_in, const int* in_sizes, int n_in,
                              void* d_out, int out_size, void* d_ws, size_t ws_size,
                              hipStream_t stream) {
  const float* x      = (const float*)d_in[0];
  const float* enc_W  = (const float*)d_in[1];
  const float* enc_b  = (const float*)d_in[2];
  const float* conv_W = (const float*)d_in[3];
  const float* conv_b = (const float*)d_in[4];
  const float* dec_W  = (const float*)d_in[5];
  const float* dec_b  = (const float*)d_in[6];
  const int*   erow   = (const int*)d_in[7];            // edge_index[0], sources
  const int*   ecol   = ((const int*)d_in[7]) + NE;     // edge_index[1], targets
  const int*   batch  = (const int*)d_in[8];
  float* out = (float*)d_out;

  // workspace layout (all 4-byte elems)
  float* h       = (float*)d_ws;                    // NN*128
  float* m       = h + (size_t)NN * 128;            // NN*128
  float* dinv    = m + (size_t)NN * 128;            // NN
  float* g       = dinv + ((NN + 255) & ~255);      // N_GRAPHS*HID
  int*   cnt     = (int*)(g + N_GRAPHS * HID);      // NN
  int*   row_ptr = cnt + ((NN + 255) & ~255);       // NN+1
  int*   cursor  = row_ptr + ((NN + 256) & ~255);   // NN
  int*   bsum    = cursor + ((NN + 255) & ~255);    // 512
  int*   csr_src = bsum + 512;                      // NE

  const int gemmBlocks = (NN + 127) / 128;
  const int nodeBlocks = (NN * 32 + 255) / 256;

  // ---- CSR build + norms ----
  zero_kernel<<<(NN + 255) / 256, 256, 0, stream>>>(cnt, g);
  cnt_count<<<(NE + 255) / 256, 256, 0, stream>>>(ecol, cnt);
  scan_partial<<<NB_SCAN, 256, 0, stream>>>(cnt, bsum);
  scan_bsum<<<1, 512, 0, stream>>>(bsum);
  scan_write<<<NB_SCAN, 256, 0, stream>>>(cnt, bsum, row_ptr, cursor, dinv);
  fill_csr<<<(NE + 255) / 256, 256, 0, stream>>>(erow, ecol, cursor, csr_src);

  // ---- encode ----
  gemm128v2<<<gemmBlocks, 256, 0, stream>>>(x, enc_W, h, enc_b, 1, nullptr, NN);

  // ---- conv layers: m' = (h@W)*dinv, then fused gather+self+bias+relu ----
  for (int l = 0; l < N_CONV; ++l) {
    const float* Wl = conv_W + (size_t)l * 128 * 128;
    const float* bl = conv_b + (size_t)l * 128;
    gemm128v2<<<gemmBlocks, 256, 0, stream>>>(h, Wl, m, nullptr, 0, dinv, NN);
    gather_fused<<<nodeBlocks, 256, 0, stream>>>(m, row_ptr, csr_src, dinv, bl, h);
  }

  // ---- pooling + decode ----
  pool_kernel<<<2048, 128, 0, stream>>>(h, batch, g);
  decode_kernel<<<(N_GRAPHS * OUT_DIM + 255) / 256, 256, 0, stream>>>(g, dec_W, dec_b, out);
}

// Round 5
// 935.648 us; speedup vs baseline: 1.3142x; 1.1377x over previous
//
#include <hip/hip_runtime.h>

#define NN 100000
#define NE 1600000
#define HID 128
#define OUT_DIM 10
#define N_CONV 4
#define N_GRAPHS 128

#define NBUCK 196                      // ceil(NN / 512) coarse dst-buckets
#define CCHUNK 4096                    // edges per scatter block
#define NCB ((NE + CCHUNK - 1) / CCHUNK)   // 391 blocks

// ---------------- zero: pool accumulator + coarse histogram ----------------

__global__ __launch_bounds__(256) void k_zero(float* __restrict__ g,
                                              int* __restrict__ coarse_cnt) {
  int i = blockIdx.x * 256 + threadIdx.x;
  if (i < N_GRAPHS * HID) g[i] = 0.0f;
  if (i < NBUCK + 1) coarse_cnt[i] = 0;
}

// ---------------- coarse histogram over dst>>9 ----------------

__global__ __launch_bounds__(256) void k_hist(const int* __restrict__ ecol,
                                              int* __restrict__ coarse_cnt) {
  __shared__ int cnt[NBUCK];
  for (int i = threadIdx.x; i < NBUCK; i += 256) cnt[i] = 0;
  __syncthreads();
  int base = blockIdx.x * CCHUNK;
#pragma unroll
  for (int i = 0; i < 16; ++i) {
    int e = base + i * 256 + threadIdx.x;
    if (e < NE) atomicAdd(&cnt[ecol[e] >> 9], 1);
  }
  __syncthreads();
  for (int i = threadIdx.x; i < NBUCK; i += 256)
    if (cnt[i]) atomicAdd(&coarse_cnt[i], cnt[i]);
}

// ---------------- scan coarse buckets -> bases, init cursors ----------------

__global__ __launch_bounds__(256) void k_scanb(const int* __restrict__ coarse_cnt,
                                               int* __restrict__ bucket_base,
                                               int* __restrict__ bcur,
                                               int* __restrict__ row_ptr) {
  __shared__ int s[256];
  int t = threadIdx.x;
  int v = (t < NBUCK) ? coarse_cnt[t] : 0;
  s[t] = v;
  __syncthreads();
  for (int off = 1; off < 256; off <<= 1) {
    int u = (t >= off) ? s[t - off] : 0;
    __syncthreads();
    s[t] += u;
    __syncthreads();
  }
  if (t < NBUCK) {
    int excl = s[t] - v;
    bucket_base[t] = excl;
    bcur[t] = excl;
  }
  if (t == 0) { bucket_base[NBUCK] = NE; row_ptr[NN] = NE; }
}

// ---- scatter edges into coarse-bucket regions with LDS reorder (locality) ----
// edge_buf entry: src | (dst&511)<<17   (src<2^17, dlocal<2^9 -> 26 bits)

__global__ __launch_bounds__(256) void k_scatter(const int* __restrict__ erow,
                                                 const int* __restrict__ ecol,
                                                 int* __restrict__ bcur,
                                                 int* __restrict__ edge_buf) {
  __shared__ int rs[CCHUNK];
  __shared__ unsigned char rb[CCHUNK];
  __shared__ int cnt[NBUCK + 1];
  __shared__ int lbase[NBUCK + 1];
  __shared__ int lcur[NBUCK + 1];
  __shared__ int grun[NBUCK];
  __shared__ int sscan[256];
  __shared__ int sTotal;

  const int t = threadIdx.x;
  const int base = blockIdx.x * CCHUNK;

  for (int i = t; i < NBUCK + 1; i += 256) cnt[i] = 0;
  __syncthreads();

  int myb[16];
#pragma unroll
  for (int i = 0; i < 16; ++i) {
    int e = base + i * 256 + t;
    int b = NBUCK;
    if (e < NE) b = ecol[e] >> 9;
    myb[i] = b;
    if (b < NBUCK) atomicAdd(&cnt[b], 1);
  }
  __syncthreads();

  // exclusive scan of cnt[0..NBUCK)
  int cv = (t < NBUCK) ? cnt[t] : 0;
  sscan[t] = cv;
  __syncthreads();
  for (int off = 1; off < 256; off <<= 1) {
    int u = (t >= off) ? sscan[t - off] : 0;
    __syncthreads();
    sscan[t] += u;
    __syncthreads();
  }
  if (t < NBUCK) {
    int excl = sscan[t] - cv;
    lbase[t] = excl;
    lcur[t] = excl;
    if (cv > 0) grun[t] = atomicAdd(&bcur[t], cv);
  }
  if (t == 255) sTotal = sscan[255];
  __syncthreads();

  // reorder into LDS by bucket
#pragma unroll
  for (int i = 0; i < 16; ++i) {
    int b = myb[i];
    if (b < NBUCK) {
      int e = base + i * 256 + t;
      int packed = erow[e] | ((ecol[e] & 511) << 17);
      int pos = atomicAdd(&lcur[b], 1);
      rs[pos] = packed;
      rb[pos] = (unsigned char)b;
    }
  }
  __syncthreads();

  // copy out contiguous runs
  int total = sTotal;
  for (int pos = t; pos < total; pos += 256) {
    int b = rb[pos];
    edge_buf[grun[b] + (pos - lbase[b])] = rs[pos];
  }
}

// ---- per-bucket CSR build: counts, row_ptr, dinv, src scatter (L2-local) ----

__global__ __launch_bounds__(512) void k_build(const int* __restrict__ bucket_base,
                                               const int* __restrict__ edge_buf,
                                               int* __restrict__ row_ptr,
                                               float* __restrict__ dinv,
                                               int* __restrict__ csr_src) {
  __shared__ int cnt[512];
  __shared__ int s[512];
  __shared__ int cur[512];
  const int b = blockIdx.x;
  const int t = threadIdx.x;
  const int r0 = bucket_base[b];
  const int r1 = bucket_base[b + 1];

  cnt[t] = 0;
  __syncthreads();
  for (int e = r0 + t; e < r1; e += 512) {
    int dl = ((unsigned)edge_buf[e]) >> 17;
    atomicAdd(&cnt[dl], 1);
  }
  __syncthreads();
  s[t] = cnt[t];
  __syncthreads();
  for (int off = 1; off < 512; off <<= 1) {
    int u = (t >= off) ? s[t - off] : 0;
    __syncthreads();
    s[t] += u;
    __syncthreads();
  }
  int node = b * 512 + t;
  int excl = s[t] - cnt[t];
  if (node < NN) {
    row_ptr[node] = r0 + excl;
    dinv[node] = rsqrtf((float)(cnt[t] + 1));  // +1 self-loop
  }
  cur[t] = r0 + excl;
  __syncthreads();
  for (int e = r0 + t; e < r1; e += 512) {
    int v = edge_buf[e];
    int dl = ((unsigned)v) >> 17;
    int pos = atomicAdd(&cur[dl], 1);
    csr_src[pos] = v & 0x1FFFF;
  }
}

// ---------------- fp32 GEMM: out[N,128] = A[N,128] @ W[128,128] ----------------

__global__ __launch_bounds__(256) void gemm128v2(const float* __restrict__ A,
                                                 const float* __restrict__ W,
                                                 float* __restrict__ out,
                                                 const float* __restrict__ bias,
                                                 int relu,
                                                 const float* __restrict__ rowscale,
                                                 int N) {
  __shared__ float sA[128][36];
  __shared__ float sW[32][132];
  const int tid = threadIdx.x;
  const int tr = tid >> 4;   // 0..15
  const int tc = tid & 15;   // 0..15
  const int rowBase = blockIdx.x * 128;

  float4 acc0[8], acc1[8];
#pragma unroll
  for (int r = 0; r < 8; ++r) {
    acc0[r] = make_float4(0.f, 0.f, 0.f, 0.f);
    acc1[r] = make_float4(0.f, 0.f, 0.f, 0.f);
  }

  for (int kc = 0; kc < 128; kc += 32) {
    {  // stage A tile
      int r = tid >> 1;
      int half = tid & 1;
      int row = rowBase + r;
      const float* src = &A[(size_t)row * 128 + kc + half * 16];
#pragma unroll
      for (int j = 0; j < 4; ++j) {
        float4 v = make_float4(0.f, 0.f, 0.f, 0.f);
        if (row < N) v = *(const float4*)&src[j * 4];
        *(float4*)&sA[r][half * 16 + j * 4] = v;
      }
    }
    {  // stage W tile
      int k = tid >> 3;
      int cg = (tid & 7) * 16;
      const float* src = &W[(size_t)(kc + k) * 128 + cg];
#pragma unroll
      for (int j = 0; j < 4; ++j) {
        *(float4*)&sW[k][cg + j * 4] = *(const float4*)&src[j * 4];
      }
    }
    __syncthreads();

#pragma unroll
    for (int kk = 0; kk < 32; kk += 4) {
      float4 b0[4], b1[4];
#pragma unroll
      for (int j = 0; j < 4; ++j) {
        b0[j] = *(float4*)&sW[kk + j][tc * 4];
        b1[j] = *(float4*)&sW[kk + j][tc * 4 + 64];
      }
#pragma unroll
      for (int r = 0; r < 8; ++r) {
        float4 a = *(float4*)&sA[tr + 16 * r][kk];
        acc0[r].x += a.x * b0[0].x; acc0[r].y += a.x * b0[0].y;
        acc0[r].z += a.x * b0[0].z; acc0[r].w += a.x * b0[0].w;
        acc1[r].x += a.x * b1[0].x; acc1[r].y += a.x * b1[0].y;
        acc1[r].z += a.x * b1[0].z; acc1[r].w += a.x * b1[0].w;

        acc0[r].x += a.y * b0[1].x; acc0[r].y += a.y * b0[1].y;
        acc0[r].z += a.y * b0[1].z; acc0[r].w += a.y * b0[1].w;
        acc1[r].x += a.y * b1[1].x; acc1[r].y += a.y * b1[1].y;
        acc1[r].z += a.y * b1[1].z; acc1[r].w += a.y * b1[1].w;

        acc0[r].x += a.z * b0[2].x; acc0[r].y += a.z * b0[2].y;
        acc0[r].z += a.z * b0[2].z; acc0[r].w += a.z * b0[2].w;
        acc1[r].x += a.z * b1[2].x; acc1[r].y += a.z * b1[2].y;
        acc1[r].z += a.z * b1[2].z; acc1[r].w += a.z * b1[2].w;

        acc0[r].x += a.w * b0[3].x; acc0[r].y += a.w * b0[3].y;
        acc0[r].z += a.w * b0[3].z; acc0[r].w += a.w * b0[3].w;
        acc1[r].x += a.w * b1[3].x; acc1[r].y += a.w * b1[3].y;
        acc1[r].z += a.w * b1[3].z; acc1[r].w += a.w * b1[3].w;
      }
    }
    __syncthreads();
  }

  float4 bv0 = make_float4(0.f, 0.f, 0.f, 0.f);
  float4 bv1 = make_float4(0.f, 0.f, 0.f, 0.f);
  if (bias) {
    bv0 = *(const float4*)&bias[tc * 4];
    bv1 = *(const float4*)&bias[tc * 4 + 64];
  }
#pragma unroll
  for (int r = 0; r < 8; ++r) {
    int row = rowBase + tr + 16 * r;
    if (row < N) {
      float sc = rowscale ? rowscale[row] : 1.0f;
      float4 v0, v1;
      v0.x = (acc0[r].x + bv0.x) * sc; v0.y = (acc0[r].y + bv0.y) * sc;
      v0.z = (acc0[r].z + bv0.z) * sc; v0.w = (acc0[r].w + bv0.w) * sc;
      v1.x = (acc1[r].x + bv1.x) * sc; v1.y = (acc1[r].y + bv1.y) * sc;
      v1.z = (acc1[r].z + bv1.z) * sc; v1.w = (acc1[r].w + bv1.w) * sc;
      if (relu) {
        v0.x = fmaxf(v0.x, 0.f); v0.y = fmaxf(v0.y, 0.f);
        v0.z = fmaxf(v0.z, 0.f); v0.w = fmaxf(v0.w, 0.f);
        v1.x = fmaxf(v1.x, 0.f); v1.y = fmaxf(v1.y, 0.f);
        v1.z = fmaxf(v1.z, 0.f); v1.w = fmaxf(v1.w, 0.f);
      }
      *(float4*)&out[(size_t)row * 128 + tc * 4] = v0;
      *(float4*)&out[(size_t)row * 128 + tc * 4 + 64] = v1;
    }
  }
}

// ---- fused aggregation: h[i] = relu(dinv_i*(sum_in m'[src] + m'[i]) + bias) ----
// 4-deep software pipeline: 4 row loads in flight per node.

__global__ __launch_bounds__(256) void gather_fused(const float* __restrict__ m,
                                                    const int* __restrict__ row_ptr,
                                                    const int* __restrict__ csr_src,
                                                    const float* __restrict__ dinv,
                                                    const float* __restrict__ bias,
                                                    float* __restrict__ h) {
  int t = blockIdx.x * 256 + threadIdx.x;
  int node = t >> 5;
  if (node >= NN) return;
  int lane = t & 31;

  float4 a0 = *(const float4*)&m[(size_t)node * 128 + lane * 4];  // self (pre-scaled)
  float4 a1 = make_float4(0.f, 0.f, 0.f, 0.f);
  float4 a2 = make_float4(0.f, 0.f, 0.f, 0.f);
  float4 a3 = make_float4(0.f, 0.f, 0.f, 0.f);

  int beg = row_ptr[node];
  int end = row_ptr[node + 1];

  int k = beg;
  for (; k + 3 < end; k += 4) {
    int s0 = csr_src[k], s1 = csr_src[k + 1], s2 = csr_src[k + 2], s3 = csr_src[k + 3];
    float4 v0 = *(const float4*)&m[(size_t)s0 * 128 + lane * 4];
    float4 v1 = *(const float4*)&m[(size_t)s1 * 128 + lane * 4];
    float4 v2 = *(const float4*)&m[(size_t)s2 * 128 + lane * 4];
    float4 v3 = *(const float4*)&m[(size_t)s3 * 128 + lane * 4];
    a0.x += v0.x; a0.y += v0.y; a0.z += v0.z; a0.w += v0.w;
    a1.x += v1.x; a1.y += v1.y; a1.z += v1.z; a1.w += v1.w;
    a2.x += v2.x; a2.y += v2.y; a2.z += v2.z; a2.w += v2.w;
    a3.x += v3.x; a3.y += v3.y; a3.z += v3.z; a3.w += v3.w;
  }
  for (; k < end; ++k) {
    int s = csr_src[k];
    float4 v = *(const float4*)&m[(size_t)s * 128 + lane * 4];
    a0.x += v.x; a0.y += v.y; a0.z += v.z; a0.w += v.w;
  }
  a0.x += a1.x + a2.x + a3.x;
  a0.y += a1.y + a2.y + a3.y;
  a0.z += a1.z + a2.z + a3.z;
  a0.w += a1.w + a2.w + a3.w;

  float dn = dinv[node];
  float4 b = *(const float4*)&bias[lane * 4];
  float4 o;
  o.x = fmaxf(a0.x * dn + b.x, 0.f);
  o.y = fmaxf(a0.y * dn + b.y, 0.f);
  o.z = fmaxf(a0.z * dn + b.z, 0.f);
  o.w = fmaxf(a0.w * dn + b.w, 0.f);
  *(float4*)&h[(size_t)node * 128 + lane * 4] = o;
}

// ---------------- pooling: g[batch[i]] += h[i], batch sorted ----------------

__global__ __launch_bounds__(128) void pool_kernel(const float* __restrict__ h,
                                                   const int* __restrict__ batch,
                                                   float* __restrict__ g) {
  int d = threadIdx.x;
  int chunk = (NN + gridDim.x - 1) / gridDim.x;
  int r0 = blockIdx.x * chunk;
  int r1 = min(NN, r0 + chunk);
  if (r0 >= r1) return;
  float acc = 0.f;
  int cur = batch[r0];
  for (int r = r0; r < r1; ++r) {
    int b = batch[r];
    if (b != cur) {
      atomicAdd(&g[(size_t)cur * HID + d], acc);
      acc = 0.f;
      cur = b;
    }
    acc += h[(size_t)r * HID + d];
  }
  atomicAdd(&g[(size_t)cur * HID + d], acc);
}

// ---------------- decode: out[128,10] = g @ dec_W + dec_b ----------------

__global__ __launch_bounds__(256) void decode_kernel(const float* __restrict__ g,
                                                     const float* __restrict__ W,
                                                     const float* __restrict__ b,
                                                     float* __restrict__ out) {
  int idx = blockIdx.x * 256 + threadIdx.x;
  if (idx >= N_GRAPHS * OUT_DIM) return;
  int gi = idx / OUT_DIM;
  int o = idx % OUT_DIM;
  float acc = b[o];
#pragma unroll 8
  for (int k = 0; k < HID; ++k) acc += g[(size_t)gi * HID + k] * W[k * OUT_DIM + o];
  out[idx] = acc;
}

// ---------------- launch ----------------

extern "C" void kernel_launch(void* const* d_in, const int* in_sizes, int n_in,
                              void* d_out, int out_size, void* d_ws, size_t ws_size,
                              hipStream_t stream) {
  const float* x      = (const float*)d_in[0];
  const float* enc_W  = (const float*)d_in[1];
  const float* enc_b  = (const float*)d_in[2];
  const float* conv_W = (const float*)d_in[3];
  const float* conv_b = (const float*)d_in[4];
  const float* dec_W  = (const float*)d_in[5];
  const float* dec_b  = (const float*)d_in[6];
  const int*   erow   = (const int*)d_in[7];
  const int*   ecol   = ((const int*)d_in[7]) + NE;
  const int*   batch  = (const int*)d_in[8];
  float* out = (float*)d_out;

  float* h          = (float*)d_ws;               // 12.8M f
  float* m          = h + (size_t)12800000;       // 12.8M f
  float* dinv       = m + (size_t)12800000;       // 100352 f
  float* g          = dinv + 100352;              // 16384 f
  int*   row_ptr    = (int*)(g + 16384);          // 100352 i (NN+1 used)
  int*   csr_src    = row_ptr + 100352;           // 1.6M i
  int*   edge_buf   = csr_src + 1600000;          // 1.6M i
  int*   coarse_cnt = edge_buf + 1600000;         // 256 i
  int*   bucket_base= coarse_cnt + 256;           // 256 i
  int*   bcur       = bucket_base + 256;          // 256 i

  const int gemmBlocks = (NN + 127) / 128;
  const int nodeBlocks = (NN * 32 + 255) / 256;

  // ---- CSR build (two-level counting sort) ----
  k_zero<<<64, 256, 0, stream>>>(g, coarse_cnt);
  k_hist<<<NCB, 256, 0, stream>>>(ecol, coarse_cnt);
  k_scanb<<<1, 256, 0, stream>>>(coarse_cnt, bucket_base, bcur, row_ptr);
  k_scatter<<<NCB, 256, 0, stream>>>(erow, ecol, bcur, edge_buf);
  k_build<<<NBUCK, 512, 0, stream>>>(bucket_base, edge_buf, row_ptr, dinv, csr_src);

  // ---- encode ----
  gemm128v2<<<gemmBlocks, 256, 0, stream>>>(x, enc_W, h, enc_b, 1, nullptr, NN);

  // ---- conv layers ----
  for (int l = 0; l < N_CONV; ++l) {
    const float* Wl = conv_W + (size_t)l * 128 * 128;
    const float* bl = conv_b + (size_t)l * 128;
    gemm128v2<<<gemmBlocks, 256, 0, stream>>>(h, Wl, m, nullptr, 0, dinv, NN);
    gather_fused<<<nodeBlocks, 256, 0, stream>>>(m, row_ptr, csr_src, dinv, bl, h);
  }

  // ---- pooling + decode ----
  pool_kernel<<<2048, 128, 0, stream>>>(h, batch, g);
  decode_kernel<<<(N_GRAPHS * OUT_DIM + 255) / 256, 256, 0, stream>>>(g, dec_W, dec_b, out);
}